// Round 1
// baseline (3384.360 us; speedup 1.0000x reference)
//
#include <hip/hip_runtime.h>

// Problem constants (B=16, S=512, D=1024, H=16, DK=64)
#define SEQ    512
#define NH     16
#define HDIM   64
#define DMODEL 1024
#define MROWS  8192              // B*S
#define OUT_ELEMS   8388608ll   // B*S*D
#define ATTN_ELEMS  67108864ll  // B*H*S*S

// ---------------------------------------------------------------------------
// Generic NN GEMM: C = A[M=8192, K] @ W[K, N] + bias[N], with scatter-store:
//   i -> (b = i>>9, s = i&511); j -> (h = j>>cl, c = j & (chunk-1))
//   dst = ((b*Hn + h)*SEQ + s)*chunk + c
//   K1 qkv: Hn=16, cl=6  -> [B,H,S,DK]
//   K2 g:   Hn=16, cl=9  -> [B,H,S,S] (into attn slot)
//   K4 out: Hn=1,  cl=10 -> row-major [B*S, D]
// 128x128 tile, BK=16, 256 threads, 8x8 micro-tile (split 4+4 rows/cols for
// coalesced stores + conflict-free LDS reads).
// ---------------------------------------------------------------------------
__global__ __launch_bounds__(256)
void gemm_nn(const float* __restrict__ A, const float* __restrict__ W,
             const float* __restrict__ bias, float* __restrict__ Cdst,
             int N, int K, int Hn, int cl)
{
    __shared__ float sA[16][132];   // A tile transposed: sA[kk][row], pad->2-way max
    __shared__ float sB[16][128];   // W tile: sB[kk][col]

    const int t  = threadIdx.x;
    const int i0 = blockIdx.y * 128;
    const int j0 = blockIdx.x * 128;
    const int ty = t >> 4, tx = t & 15;

    float acc[8][8];
#pragma unroll
    for (int a = 0; a < 8; ++a)
#pragma unroll
        for (int b = 0; b < 8; ++b) acc[a][b] = 0.f;

    for (int k0 = 0; k0 < K; k0 += 16) {
#pragma unroll
        for (int l = 0; l < 2; ++l) {                 // A tile 128x16
            int f = t + l * 256;
            int row = f >> 2, c4 = (f & 3) * 4;
            const float4 va = *(const float4*)&A[(size_t)(i0 + row) * K + k0 + c4];
            sA[c4 + 0][row] = va.x; sA[c4 + 1][row] = va.y;
            sA[c4 + 2][row] = va.z; sA[c4 + 3][row] = va.w;
        }
#pragma unroll
        for (int l = 0; l < 2; ++l) {                 // W tile 16x128
            int f = t + l * 256;
            int r = f >> 5, c4 = (f & 31) * 4;
            *(float4*)&sB[r][c4] = *(const float4*)&W[(size_t)(k0 + r) * N + j0 + c4];
        }
        __syncthreads();
#pragma unroll
        for (int kk = 0; kk < 16; ++kk) {
            float4 a0 = *(const float4*)&sA[kk][ty * 4];
            float4 a1 = *(const float4*)&sA[kk][64 + ty * 4];
            float4 b0 = *(const float4*)&sB[kk][tx * 4];
            float4 b1 = *(const float4*)&sB[kk][64 + tx * 4];
            float ra[8] = {a0.x, a0.y, a0.z, a0.w, a1.x, a1.y, a1.z, a1.w};
            float rb[8] = {b0.x, b0.y, b0.z, b0.w, b1.x, b1.y, b1.z, b1.w};
#pragma unroll
            for (int a = 0; a < 8; ++a)
#pragma unroll
                for (int b = 0; b < 8; ++b) acc[a][b] += ra[a] * rb[b];
        }
        __syncthreads();
    }

    const int chunk = 1 << cl;
#pragma unroll
    for (int a = 0; a < 8; ++a) {
        int i  = i0 + (a < 4 ? ty * 4 + a : 64 + ty * 4 + (a - 4));
        int bb = i >> 9, s = i & 511;
#pragma unroll
        for (int g = 0; g < 2; ++g) {
            int j = j0 + (g ? 64 + tx * 4 : tx * 4);
            int h = j >> cl, c = j & (chunk - 1);
            size_t dst = ((size_t)(bb * Hn + h) * SEQ + s) * chunk + c;
            float4 r;
            r.x = acc[a][g * 4 + 0] + bias[j + 0];
            r.y = acc[a][g * 4 + 1] + bias[j + 1];
            r.z = acc[a][g * 4 + 2] + bias[j + 2];
            r.w = acc[a][g * 4 + 3] + bias[j + 3];
            *(float4*)&Cdst[dst] = r;
        }
    }
}

// ---------------------------------------------------------------------------
// scores[b,h,i,j] = scale * dot(q[b,h,i,:], k[b,h,j,:]) + prev[b,h,i,j]
// Batched over 256 (b,h); per batch 512x512, K=64. 64x64 tile, 4x4 micro.
// ---------------------------------------------------------------------------
__global__ __launch_bounds__(256)
void scores_kernel(const float* __restrict__ q_ws, const float* __restrict__ k_ws,
                   const float* __restrict__ prev, const float* __restrict__ scale_p,
                   float* __restrict__ scores)
{
    const int bid   = blockIdx.x;
    const int batch = bid >> 6;              // 64 tiles per (b,h)
    const int tile  = bid & 63;
    const int i0    = (tile >> 3) * 64;
    const int j0    = (tile & 7) * 64;
    const float* q = q_ws + (size_t)batch * SEQ * HDIM;
    const float* k = k_ws + (size_t)batch * SEQ * HDIM;
    const float scale = *scale_p;

    __shared__ float sA[16][68];   // q  transposed: sA[kk][i]
    __shared__ float sB[16][68];   // k  transposed: sB[kk][j]
    const int t = threadIdx.x;
    const int ty = t >> 4, tx = t & 15;
    float acc[4][4] = {};

    for (int k0 = 0; k0 < HDIM; k0 += 16) {
        int row = t >> 2, c4 = (t & 3) * 4;
        float4 va = *(const float4*)&q[(size_t)(i0 + row) * HDIM + k0 + c4];
        sA[c4 + 0][row] = va.x; sA[c4 + 1][row] = va.y;
        sA[c4 + 2][row] = va.z; sA[c4 + 3][row] = va.w;
        float4 vb = *(const float4*)&k[(size_t)(j0 + row) * HDIM + k0 + c4];
        sB[c4 + 0][row] = vb.x; sB[c4 + 1][row] = vb.y;
        sB[c4 + 2][row] = vb.z; sB[c4 + 3][row] = vb.w;
        __syncthreads();
#pragma unroll
        for (int kk = 0; kk < 16; ++kk) {
            float4 a = *(const float4*)&sA[kk][ty * 4];
            float4 b = *(const float4*)&sB[kk][tx * 4];
            float ra[4] = {a.x, a.y, a.z, a.w};
            float rb[4] = {b.x, b.y, b.z, b.w};
#pragma unroll
            for (int x = 0; x < 4; ++x)
#pragma unroll
                for (int y = 0; y < 4; ++y) acc[x][y] += ra[x] * rb[y];
        }
        __syncthreads();
    }

#pragma unroll
    for (int x = 0; x < 4; ++x) {
        int i = i0 + ty * 4 + x;
        size_t base = ((size_t)batch * SEQ + i) * SEQ + j0 + tx * 4;
        float4 pv = *(const float4*)&prev[base];
        float4 r;
        r.x = acc[x][0] * scale + pv.x;
        r.y = acc[x][1] * scale + pv.y;
        r.z = acc[x][2] * scale + pv.z;
        r.w = acc[x][3] * scale + pv.w;
        *(float4*)&scores[base] = r;
    }
}

// ---------------------------------------------------------------------------
// Row softmax + gating: attn = g * softmax(scores, axis=-1).
// One wave (64 lanes) per row of 512. g lives in the attn slot (in-place).
// ---------------------------------------------------------------------------
__global__ __launch_bounds__(256)
void softmax_gate(const float* __restrict__ scores, float* __restrict__ attn)
{
    const int row = blockIdx.x * 4 + (threadIdx.x >> 6);
    const int l   = threadIdx.x & 63;
    const size_t base = (size_t)row * SEQ;

    float4 x0 = *(const float4*)&scores[base + l * 4];
    float4 x1 = *(const float4*)&scores[base + 256 + l * 4];
    float xs[8] = {x0.x, x0.y, x0.z, x0.w, x1.x, x1.y, x1.z, x1.w};

    float m = xs[0];
#pragma unroll
    for (int i = 1; i < 8; ++i) m = fmaxf(m, xs[i]);
#pragma unroll
    for (int o = 1; o < 64; o <<= 1) m = fmaxf(m, __shfl_xor(m, o));

    float es[8];
    float sum = 0.f;
#pragma unroll
    for (int i = 0; i < 8; ++i) { es[i] = __expf(xs[i] - m); sum += es[i]; }
#pragma unroll
    for (int o = 1; o < 64; o <<= 1) sum += __shfl_xor(sum, o);
    const float inv = 1.0f / sum;

    float4 g0 = *(const float4*)&attn[base + l * 4];
    float4 g1 = *(const float4*)&attn[base + 256 + l * 4];
    float4 r0, r1;
    r0.x = g0.x * es[0] * inv; r0.y = g0.y * es[1] * inv;
    r0.z = g0.z * es[2] * inv; r0.w = g0.w * es[3] * inv;
    r1.x = g1.x * es[4] * inv; r1.y = g1.y * es[5] * inv;
    r1.z = g1.z * es[6] * inv; r1.w = g1.w * es[7] * inv;
    *(float4*)&attn[base + l * 4]       = r0;
    *(float4*)&attn[base + 256 + l * 4] = r1;
}

// ---------------------------------------------------------------------------
// o[b,s,h,:] = attn[b,h,s,:] @ v[b,h,:,:]   (per batch: 512x64 = 512x512 @ 512x64)
// Output layout [B,S,H*DK] row-major so the final projection reads it as A.
// ---------------------------------------------------------------------------
__global__ __launch_bounds__(256)
void pv_kernel(const float* __restrict__ attn, const float* __restrict__ v_ws,
               float* __restrict__ o_ws)
{
    const int bid   = blockIdx.x;
    const int batch = bid >> 3;             // 8 row-tiles per (b,h)
    const int i0    = (bid & 7) * 64;
    const float* A = attn + (size_t)batch * SEQ * SEQ;
    const float* V = v_ws + (size_t)batch * SEQ * HDIM;
    const int b = batch >> 4, h = batch & 15;

    __shared__ float sA[16][68];  // attn transposed: sA[kk][i]
    __shared__ float sB[16][64];  // v: sB[kk][d]
    const int t = threadIdx.x;
    const int ty = t >> 4, tx = t & 15;
    float acc[4][4] = {};

    for (int k0 = 0; k0 < SEQ; k0 += 16) {
        int row = t >> 2, c4 = (t & 3) * 4;
        float4 va = *(const float4*)&A[(size_t)(i0 + row) * SEQ + k0 + c4];
        sA[c4 + 0][row] = va.x; sA[c4 + 1][row] = va.y;
        sA[c4 + 2][row] = va.z; sA[c4 + 3][row] = va.w;
        int r = t >> 4, c44 = (t & 15) * 4;
        *(float4*)&sB[r][c44] = *(const float4*)&V[(size_t)(k0 + r) * HDIM + c44];
        __syncthreads();
#pragma unroll
        for (int kk = 0; kk < 16; ++kk) {
            float4 a = *(const float4*)&sA[kk][ty * 4];
            float4 bv = *(const float4*)&sB[kk][tx * 4];
            float ra[4] = {a.x, a.y, a.z, a.w};
            float rb[4] = {bv.x, bv.y, bv.z, bv.w};
#pragma unroll
            for (int x = 0; x < 4; ++x)
#pragma unroll
                for (int y = 0; y < 4; ++y) acc[x][y] += ra[x] * rb[y];
        }
        __syncthreads();
    }

#pragma unroll
    for (int x = 0; x < 4; ++x) {
        int i = i0 + ty * 4 + x;
        size_t dst = ((size_t)(b * SEQ + i) * NH + h) * HDIM + tx * 4;
        float4 r = {acc[x][0], acc[x][1], acc[x][2], acc[x][3]};
        *(float4*)&o_ws[dst] = r;
    }
}

// ---------------------------------------------------------------------------
extern "C" void kernel_launch(void* const* d_in, const int* in_sizes, int n_in,
                              void* d_out, int out_size, void* d_ws, size_t ws_size,
                              hipStream_t stream)
{
    const float* Q     = (const float*)d_in[0];
    const float* prev  = (const float*)d_in[1];
    const float* Wq    = (const float*)d_in[2];
    const float* bq    = (const float*)d_in[3];
    const float* Wk    = (const float*)d_in[4];
    const float* bk    = (const float*)d_in[5];
    const float* Wv    = (const float*)d_in[6];
    const float* bv    = (const float*)d_in[7];
    const float* Wg    = (const float*)d_in[8];
    const float* bg    = (const float*)d_in[9];
    const float* Wo    = (const float*)d_in[10];
    const float* bo    = (const float*)d_in[11];
    const float* scale = (const float*)d_in[12];

    float* out    = (float*)d_out;                 // [B,S,D]
    float* attn   = out + OUT_ELEMS;               // [B,H,S,S] (holds g temporarily)
    float* scores = attn + ATTN_ELEMS;             // [B,H,S,S]

    float* q_ws = (float*)d_ws;                    // [B,H,S,DK] 32 MiB
    float* k_ws = q_ws + OUT_ELEMS;
    float* v_ws = k_ws + OUT_ELEMS;
    float* o_ws = q_ws;                            // q dead after scores_kernel

    dim3 blk(256);
    // projections -> [B,H,S,DK]
    gemm_nn<<<dim3(DMODEL / 128, MROWS / 128), blk, 0, stream>>>(Q, Wq, bq, q_ws, DMODEL, DMODEL, NH, 6);
    gemm_nn<<<dim3(DMODEL / 128, MROWS / 128), blk, 0, stream>>>(Q, Wk, bk, k_ws, DMODEL, DMODEL, NH, 6);
    gemm_nn<<<dim3(DMODEL / 128, MROWS / 128), blk, 0, stream>>>(Q, Wv, bv, v_ws, DMODEL, DMODEL, NH, 6);
    // gating GEMM -> g stored in attn slot as [B,H,S,S]
    gemm_nn<<<dim3(8192 / 128, MROWS / 128), blk, 0, stream>>>(Q, Wg, bg, attn, 8192, DMODEL, NH, 9);
    // scores = scale*q.k^T + prev
    scores_kernel<<<256 * 64, blk, 0, stream>>>(q_ws, k_ws, prev, scale, scores);
    // attn = g * softmax(scores)
    softmax_gate<<<(16 * NH * SEQ) / 4, blk, 0, stream>>>(scores, attn);
    // o = attn @ v -> [B,S,D] (into q_ws)
    pv_kernel<<<256 * 8, blk, 0, stream>>>(attn, v_ws, o_ws);
    // out = o @ Wo + bo
    gemm_nn<<<dim3(DMODEL / 128, MROWS / 128), blk, 0, stream>>>(o_ws, Wo, bo, out, DMODEL, DMODEL, 1, 10);
}